// Round 17
// baseline (312.519 us; speedup 1.0000x reference)
//
#include <hip/hip_runtime.h>
#include <hip/hip_bf16.h>

typedef __attribute__((ext_vector_type(8))) short short8;
typedef __attribute__((ext_vector_type(4))) float f32x4;

namespace {
constexpr int B_ = 4, H_ = 8, L_ = 4096, D_ = 128, S_ = 1024;
constexpr int NTOK = B_ * H_ * L_;          // 131072
constexpr int SCAN_BLK = 256;               // 4 waves
constexpr int SCAN_TPW = 32, SCAN_TPB = 128;
constexpr int SCAN_GRID = NTOK / SCAN_TPB;  // 1024
constexpr int NCHUNK = 32;                  // 2 s-tiles (32 codes) per chunk
constexpr double FPSCALE = 1048576.0;       // 2^20 fixed point

// ws: acc | c_hi (frag-major) | c_lo | Bn | inv | Bq
constexpr size_t WS_ACC  = 0;
constexpr size_t WS_CHI  = 64;
constexpr size_t WS_CLO  = WS_CHI + 2ull * H_ * S_ * D_;
constexpr size_t WS_BN   = WS_CLO + 2ull * H_ * S_ * D_;
constexpr size_t WS_INV  = WS_BN + 4ull * H_ * S_;
constexpr size_t WS_BQ   = WS_INV + 4ull * H_ * S_;
}

__device__ inline void atomAddFixed(unsigned long long* p, double v) {
    long long q = __double2ll_rn(v * FPSCALE);
    atomicAdd(p, (unsigned long long)q);
}
__device__ inline unsigned short bf_hi(float x) {
    __hip_bfloat16 h = __float2bfloat16(x);
    unsigned short u; __builtin_memcpy(&u, &h, 2); return u;
}
__device__ inline float bf_f(unsigned short u) {
    __hip_bfloat16 h; __builtin_memcpy(&h, &u, 2); return __bfloat162float(h);
}

// ---------------------------------------------------------------------------
// Prep: normalize codebook, split bf16 hi/lo into MFMA-fragment-major layout:
// bf16 index = (h*64+st)*2048 + ck*512 + (kg*16+col)*8 + j
//   for s = st*16+col, d = ck*32+kg*8+j.
// ---------------------------------------------------------------------------
__global__ __launch_bounds__(64) void vq_prep(
    const float* __restrict__ c_sum, const float* __restrict__ c_count,
    unsigned short* __restrict__ c_hi, unsigned short* __restrict__ c_lo,
    float* __restrict__ Bn, float* __restrict__ inv, float* __restrict__ Bq,
    unsigned long long* __restrict__ acc) {
    int hs = blockIdx.x, lane = threadIdx.x;
    int h = hs >> 10, s = hs & 1023;
    int st = s >> 4, colp = s & 15;
    float cnt = c_count[hs];
    float iv = 1.0f / fmaxf(cnt, 0.01f);
    const float2 e = *reinterpret_cast<const float2*>(c_sum + (size_t)hs * D_ + 2 * lane);
    float c0 = e.x * iv, c1 = e.y * iv;
    unsigned short h0 = bf_hi(c0), h1 = bf_hi(c1);
    unsigned short l0 = bf_hi(c0 - bf_f(h0)), l1 = bf_hi(c1 - bf_f(h1));
    int d0 = 2 * lane;
    int ck = d0 >> 5, kg = (d0 >> 3) & 3, j = d0 & 7;
    size_t fidx = (size_t)(h * 64 + st) * 2048 + ck * 512 + (kg * 16 + colp) * 8 + j;
    *reinterpret_cast<ushort2*>(c_hi + fidx) = make_ushort2(h0, h1);
    *reinterpret_cast<ushort2*>(c_lo + fidx) = make_ushort2(l0, l1);
    float sqn = c0 * c0 + c1 * c1;
    float sqr = e.x * e.x + e.y * e.y;
#pragma unroll
    for (int o = 32; o; o >>= 1) { sqn += __shfl_down(sqn, o); sqr += __shfl_down(sqr, o); }
    if (lane == 0) {
        Bn[hs] = sqn;
        inv[hs] = iv;
        Bq[hs] = iv * iv * sqr;
        atomAddFixed(&acc[0], (double)sqr + (double)cnt * (double)cnt);
    }
}

#define MFMA(a, b, c) __builtin_amdgcn_mfma_f32_16x16x32_bf16(a, b, c, 0, 0, 0)

// ---------------------------------------------------------------------------
// Fused scan + rescore: r13's proven scan loop (4 waves, 2-tile chunks,
// 32KB LDS dbuf, 139us) + r7's proven rescore/outputs epilogue, with
// candidates handed over through LDS. Epilogues of early blocks overlap
// later blocks' MFMA scans (4 blocks/CU).
// ---------------------------------------------------------------------------
__global__ __launch_bounds__(SCAN_BLK) void vq_scan(
    const float* __restrict__ vecs, const float* __restrict__ c_sum,
    const float* __restrict__ c_count, const int* __restrict__ lmask,
    const unsigned short* __restrict__ c_hi, const unsigned short* __restrict__ c_lo,
    const float* __restrict__ Bn, const float* __restrict__ inv_a,
    const float* __restrict__ Bq, unsigned long long* __restrict__ acc,
    float* __restrict__ out_hat, float* __restrict__ out_z) {
    const int tid = threadIdx.x;
    const int wave = tid >> 6, lane = tid & 63;
    const int col = lane & 15, kg = lane >> 4;
    // XCD-aware bijective swizzle (1024 % 8 == 0): same-head blocks -> same XCD
    const int blk = ((blockIdx.x & 7) << 7) | (blockIdx.x >> 3);
    const int t0b = blk * SCAN_TPB;
    const int h = (t0b >> 12) & 7;           // block-uniform
    const int b = t0b >> 15;
    const int t0w = t0b + wave * SCAN_TPW;

    __shared__ short sB[2][2][4096];         // [buf][hi/lo][2 tiles * 2048] = 32KB
    __shared__ int s_cand[4][2 * SCAN_TPW];
    __shared__ int s_zz[4][SCAN_TPW];

    // ---- A fragments: 32 tokens, split bf16 hi/lo ----
    short8 ah[2][4], al[2][4];
#pragma unroll
    for (int mt = 0; mt < 2; ++mt)
#pragma unroll
        for (int ck = 0; ck < 4; ++ck) {
            const float* vp = vecs + (size_t)(t0w + mt * 16 + col) * D_ + ck * 32 + kg * 8;
            float4 q0 = *reinterpret_cast<const float4*>(vp);
            float4 q1 = *reinterpret_cast<const float4*>(vp + 4);
            float f[8] = {q0.x, q0.y, q0.z, q0.w, q1.x, q1.y, q1.z, q1.w};
            short8 h8, l8;
#pragma unroll
            for (int i = 0; i < 8; ++i) {
                unsigned short hu = bf_hi(f[i]);
                unsigned short lu = bf_hi(f[i] - bf_f(hu));
                h8[i] = (short)hu; l8[i] = (short)lu;
            }
            ah[mt][ck] = h8; al[mt][ck] = l8;
        }

    const float* Bnh = Bn + h * S_;
    const float4* ghi = reinterpret_cast<const float4*>(c_hi) + (size_t)h * 16384;
    const float4* glo = reinterpret_cast<const float4*>(c_lo) + (size_t)h * 16384;

    // ---- prologue: stage chunk 0 (2 tiles = 16KB) ----
    float4 sg0 = ghi[tid], sg1 = ghi[256 + tid], sg2 = glo[tid], sg3 = glo[256 + tid];
    {
        float4* pH = reinterpret_cast<float4*>(&sB[0][0][0]);
        float4* pL = reinterpret_cast<float4*>(&sB[0][1][0]);
        pH[tid] = sg0; pH[256 + tid] = sg1;
        pL[tid] = sg2; pL[256 + tid] = sg3;
    }
    __syncthreads();

    float m1[2][4], m2[2][4];
#pragma unroll
    for (int mt = 0; mt < 2; ++mt)
#pragma unroll
        for (int i = 0; i < 4; ++i) { m1[mt][i] = INFINITY; m2[mt][i] = INFINITY; }

#pragma unroll 1
    for (int c = 0; c < NCHUNK; ++c) {
        const int cur = c & 1, nxt = cur ^ 1;
        if (c + 1 < NCHUNK) {                 // issue next-chunk loads early
            const float4* gh = ghi + (size_t)(c + 1) * 512;
            const float4* gl = glo + (size_t)(c + 1) * 512;
            sg0 = gh[tid]; sg1 = gh[256 + tid]; sg2 = gl[tid]; sg3 = gl[256 + tid];
        }
#pragma unroll
        for (int tl = 0; tl < 2; ++tl) {
            const int st = c * 2 + tl;
            short8 bh[4], bl[4];
#pragma unroll
            for (int ck = 0; ck < 4; ++ck) {
                bh[ck] = *reinterpret_cast<const short8*>(&sB[cur][0][tl * 2048 + ck * 512 + lane * 8]);
                bl[ck] = *reinterpret_cast<const short8*>(&sB[cur][1][tl * 2048 + ck * 512 + lane * 8]);
            }
            // 6 independent 4-deep MFMA chains
            f32x4 pa0 = {0.f,0.f,0.f,0.f}, pb0 = {0.f,0.f,0.f,0.f}, pc0 = {0.f,0.f,0.f,0.f};
            f32x4 pa1 = {0.f,0.f,0.f,0.f}, pb1 = {0.f,0.f,0.f,0.f}, pc1 = {0.f,0.f,0.f,0.f};
#pragma unroll
            for (int ck = 0; ck < 4; ++ck) {
                pa0 = MFMA(ah[0][ck], bh[ck], pa0);
                pa1 = MFMA(ah[1][ck], bh[ck], pa1);
                pb0 = MFMA(ah[0][ck], bl[ck], pb0);
                pb1 = MFMA(ah[1][ck], bl[ck], pb1);
                pc0 = MFMA(al[0][ck], bh[ck], pc0);
                pc1 = MFMA(al[1][ck], bh[ck], pc1);
            }
            const float bsc = Bnh[st * 16 + col];   // L1/L2-hit global read
#pragma unroll
            for (int i = 0; i < 4; ++i) {
                float d = fmaf(pa0[i] + pb0[i] + pc0[i], -2.f, bsc);
                float pk = __uint_as_float((__float_as_uint(d) & 0xFFFFFFC0u) | (unsigned)st);
                bool cc = pk < m1[0][i];
                m2[0][i] = cc ? m1[0][i] : fminf(pk, m2[0][i]);
                m1[0][i] = cc ? pk : m1[0][i];
                d = fmaf(pa1[i] + pb1[i] + pc1[i], -2.f, bsc);
                pk = __uint_as_float((__float_as_uint(d) & 0xFFFFFFC0u) | (unsigned)st);
                cc = pk < m1[1][i];
                m2[1][i] = cc ? m1[1][i] : fminf(pk, m2[1][i]);
                m1[1][i] = cc ? pk : m1[1][i];
            }
        }
        if (c + 1 < NCHUNK) {                 // write-late into the other buffer
            float4* pH = reinterpret_cast<float4*>(&sB[nxt][0][0]);
            float4* pL = reinterpret_cast<float4*>(&sB[nxt][1][0]);
            pH[tid] = sg0; pH[256 + tid] = sg1;
            pL[tid] = sg2; pL[256 + tid] = sg3;
        }
        __syncthreads();
    }

    // ---- decode packed top-2, butterfly merge, candidates into LDS ----
#pragma unroll
    for (int mt = 0; mt < 2; ++mt)
#pragma unroll
        for (int i = 0; i < 4; ++i) {
            float a1v = m1[mt][i], a2v = m2[mt][i];
            int x1 = (int)((__float_as_uint(a1v) & 63u) << 4) | col;   // == s index
            int x2 = (int)((__float_as_uint(a2v) & 63u) << 4) | col;
#pragma unroll
            for (int mask = 1; mask < 16; mask <<= 1) {
                float b1 = __shfl_xor(a1v, mask), b2 = __shfl_xor(a2v, mask);
                int y1 = __shfl_xor(x1, mask), y2 = __shfl_xor(x2, mask);
                bool sw = (b1 < a1v) || (b1 == a1v && y1 < x1);
                float w1 = sw ? b1 : a1v; int wi1 = sw ? y1 : x1;
                float r  = sw ? a1v : b1; int ri  = sw ? x1 : y1;
                float w2 = sw ? b2 : a2v; int wi2 = sw ? y2 : x2;
                bool s2 = (r < w2) || (r == w2 && ri < wi2);
                a1v = w1; x1 = wi1;
                a2v = s2 ? r : w2; x2 = s2 ? ri : wi2;
            }
            if (col == 0) {
                int lt = mt * 16 + kg * 4 + i;
                s_cand[wave][2 * lt]     = x1;
                s_cand[wave][2 * lt + 1] = x2;
            }
        }

    // ---- fused rescore epilogue (r7-proven, wave-local) ----
    {
        const int lt = lane >> 1;
        const int tok = t0w + lt;
        const int cidx = s_cand[wave][2 * lt + (lane & 1)];
        const float* vp = vecs + (size_t)tok * D_;
        const float* cp = c_sum + ((size_t)h * S_ + cidx) * D_;
        float d0 = 0.f, d1 = 0.f, d2 = 0.f, d3 = 0.f, vs = 0.f;
#pragma unroll
        for (int d = 0; d < D_; d += 4) {
            float4 q = *reinterpret_cast<const float4*>(vp + d);
            float4 p = *reinterpret_cast<const float4*>(cp + d);
            d0 = fmaf(q.x, p.x, d0); d1 = fmaf(q.y, p.y, d1);
            d2 = fmaf(q.z, p.z, d2); d3 = fmaf(q.w, p.w, d3);
            vs += q.x * q.x + q.y * q.y + q.z * q.z + q.w * q.w;
        }
        float dot = (d0 + d1) + (d2 + d3);
        float iv = inv_a[h * S_ + cidx];
        float dist = vs - 2.f * (iv * dot) + Bq[h * S_ + cidx];

        float od = __shfl_xor(dist, 1);
        int oc = __shfl_xor(cidx, 1);
        float odot = __shfl_xor(dot, 1);
        bool iwin = (dist < od) || (dist == od && cidx < oc);
        float dwin = iwin ? dist : od;
        int zwin = iwin ? cidx : oc;
        float dotw = iwin ? dot : odot;

        double commit = 0.0, tokc = 0.0;
        long long mcnt = 0;
        if ((lane & 1) == 0) {
            out_z[tok] = (float)zwin;
            s_zz[wave][lt] = zwin;
            const int lm = lmask[b * L_ + (tok & (L_ - 1))];
            const float mask = (float)lm;
            commit = (double)(mask * fmaxf(dwin, 0.f));
            tokc = (double)mask * ((double)dotw + (double)c_count[h * S_ + zwin]);
            if (h == 0) mcnt = lm;
        }
#pragma unroll
        for (int o = 32; o; o >>= 1) {
            commit += __shfl_down(commit, o);
            tokc   += __shfl_down(tokc, o);
            mcnt   += __shfl_down(mcnt, o);
        }
        if (lane == 0) {
            atomAddFixed(&acc[1], commit);
            atomAddFixed(&acc[2], tokc);
            if (h == 0 && mcnt) atomicAdd(&acc[3], (unsigned long long)mcnt);
        }
    }

    // ---- vecs_hat: coalesced row gather, 64 lanes per row (wave-local) ----
#pragma unroll 1
    for (int r = 0; r < SCAN_TPW; ++r) {
        int z = s_zz[wave][r];
        float iv = inv_a[h * S_ + z];
        const float2 p = *reinterpret_cast<const float2*>(c_sum + ((size_t)h * S_ + z) * D_ + lane * 2);
        float2 o; o.x = p.x * iv; o.y = p.y * iv;
        *reinterpret_cast<float2*>(out_hat + (size_t)(t0w + r) * D_ + lane * 2) = o;
    }
}

__global__ void vq_final(const unsigned long long* __restrict__ acc,
                         float* __restrict__ out_sc) {
    if (threadIdx.x == 0) {
        double CS = (double)(long long)acc[0] / FPSCALE;
        double CM = (double)(long long)acc[1] / FPSCALE;
        double TK = (double)(long long)acc[2] / FPSCALE;
        double NT = (double)(long long)acc[3];
        if (NT < 1.0) NT = 1.0;
        out_sc[0] = (float)(CM / ((double)H_ * NT));
        out_sc[1] = (float)(0.01 * (CS - TK));
    }
}

extern "C" void kernel_launch(void* const* d_in, const int* in_sizes, int n_in,
                              void* d_out, int out_size, void* d_ws, size_t ws_size,
                              hipStream_t stream) {
    const float* vecs    = (const float*)d_in[0];
    const float* c_sum   = (const float*)d_in[1];
    const float* c_count = (const float*)d_in[2];
    const int*   lmask   = (const int*)d_in[3];

    char* ws = (char*)d_ws;
    unsigned long long* acc = (unsigned long long*)(ws + WS_ACC);
    unsigned short* c_hi = (unsigned short*)(ws + WS_CHI);
    unsigned short* c_lo = (unsigned short*)(ws + WS_CLO);
    float* Bn  = (float*)(ws + WS_BN);
    float* inv = (float*)(ws + WS_INV);
    float* Bq  = (float*)(ws + WS_BQ);

    hipMemsetAsync(acc, 0, 4 * sizeof(unsigned long long), stream);

    float* out = (float*)d_out;
    float* out_sc = out + (size_t)out_size - 2;
    float* out_z  = out_sc - (size_t)NTOK;

    vq_prep<<<H_ * S_, 64, 0, stream>>>(c_sum, c_count, c_hi, c_lo, Bn, inv, Bq, acc);
    vq_scan<<<SCAN_GRID, SCAN_BLK, 0, stream>>>(vecs, c_sum, c_count, lmask, c_hi, c_lo,
                                                Bn, inv, Bq, acc, out, out_z);
    vq_final<<<1, 64, 0, stream>>>(acc, out_sc);
}

// Round 18
// 152.646 us; speedup vs baseline: 2.0473x; 2.0473x over previous
//
#include <hip/hip_runtime.h>
#include <hip/hip_bf16.h>

typedef __attribute__((ext_vector_type(8))) short short8;
typedef __attribute__((ext_vector_type(4))) float f32x4;

namespace {
constexpr int B_ = 4, H_ = 8, L_ = 4096, D_ = 128, S_ = 1024;
constexpr int NTOK = B_ * H_ * L_;          // 131072
constexpr int SCAN_BLK = 256;               // 4 waves
constexpr int SCAN_TPW = 32, SCAN_TPB = 128;
constexpr int SCAN_GRID = NTOK / SCAN_TPB;  // 1024
constexpr int NCHUNK = 32;                  // 2 s-tiles (32 codes) per chunk
constexpr int RES_TPB = 128;
constexpr int RES_GRID = NTOK / RES_TPB;    // 1024
constexpr int PREP_GRID = H_ * S_ / 16;     // 512 (16 rows per block)

// ws layout (bytes); no atomics anywhere -> per-block partial arrays
constexpr size_t WS_CHI   = 0;
constexpr size_t WS_CLO   = WS_CHI + 2ull * H_ * S_ * D_;
constexpr size_t WS_BN    = WS_CLO + 2ull * H_ * S_ * D_;
constexpr size_t WS_INV   = WS_BN + 4ull * H_ * S_;
constexpr size_t WS_BQ    = WS_INV + 4ull * H_ * S_;
constexpr size_t WS_CAND  = WS_BQ + 4ull * H_ * S_;          // NTOK u32
constexpr size_t WS_PREPP = WS_CAND + 4ull * NTOK;           // 512 doubles
constexpr size_t WS_RESC  = WS_PREPP + 8ull * PREP_GRID;     // 1024 doubles
constexpr size_t WS_REST  = WS_RESC + 8ull * RES_GRID;       // 1024 doubles
constexpr size_t WS_RESM  = WS_REST + 8ull * RES_GRID;       // 1024 ll
}

__device__ inline unsigned short bf_hi(float x) {
    __hip_bfloat16 h = __float2bfloat16(x);
    unsigned short u; __builtin_memcpy(&u, &h, 2); return u;
}
__device__ inline float bf_f(unsigned short u) {
    __hip_bfloat16 h; __builtin_memcpy(&h, &u, 2); return __bfloat162float(h);
}

// ---------------------------------------------------------------------------
// Prep: 16 lanes per (h,s) row; lane j owns d=[8j,8j+8) -> one contiguous
// short8 store into the frag-major layout. Per-block CS partial to ws.
// ---------------------------------------------------------------------------
__global__ __launch_bounds__(256) void vq_prep(
    const float* __restrict__ c_sum, const float* __restrict__ c_count,
    unsigned short* __restrict__ c_hi, unsigned short* __restrict__ c_lo,
    float* __restrict__ Bn, float* __restrict__ inv, float* __restrict__ Bq,
    double* __restrict__ prepPart) {
    const int tid = threadIdx.x;
    const int g = tid >> 4, j = tid & 15;
    const int row = blockIdx.x * 16 + g;         // hs index
    const int h = row >> 10, s = row & 1023;
    const int st = s >> 4, colp = s & 15;

    float cnt = c_count[row];
    float iv = 1.0f / fmaxf(cnt, 0.01f);
    const float4* src = reinterpret_cast<const float4*>(c_sum + (size_t)row * D_) + 2 * j;
    float4 q0 = src[0], q1 = src[1];
    float e[8] = {q0.x, q0.y, q0.z, q0.w, q1.x, q1.y, q1.z, q1.w};
    short8 h8, l8;
    float sqn = 0.f, sqr = 0.f;
#pragma unroll
    for (int i = 0; i < 8; ++i) {
        float c = e[i] * iv;
        unsigned short hu = bf_hi(c);
        unsigned short lu = bf_hi(c - bf_f(hu));
        h8[i] = (short)hu; l8[i] = (short)lu;
        sqn += c * c; sqr += e[i] * e[i];
    }
    size_t base = (size_t)(h * 64 + st) * 2048 + (j >> 2) * 512 + ((j & 3) * 16 + colp) * 8;
    *reinterpret_cast<short8*>(c_hi + base) = h8;
    *reinterpret_cast<short8*>(c_lo + base) = l8;
#pragma unroll
    for (int o = 8; o; o >>= 1) { sqn += __shfl_xor(sqn, o); sqr += __shfl_xor(sqr, o); }

    __shared__ double sP[16];
    if (j == 0) {
        Bn[row] = sqn; inv[row] = iv; Bq[row] = iv * iv * sqr;
        sP[g] = (double)sqr + (double)cnt * (double)cnt;
    }
    __syncthreads();
    if (tid == 0) {
        double t = 0.0;
#pragma unroll
        for (int i = 0; i < 16; ++i) t += sP[i];
        prepPart[blockIdx.x] = t;
    }
}

#define MFMA(a, b, c) __builtin_amdgcn_mfma_f32_16x16x32_bf16(a, b, c, 0, 0, 0)

// ---------------------------------------------------------------------------
// Scan: EXACT r13 structure (139us proven): 4 waves, 2-tile chunks, 32KB LDS
// double-buffer, split-bf16 MFMA, packed-index top-2 -> cand words.
// ---------------------------------------------------------------------------
__global__ __launch_bounds__(SCAN_BLK) void vq_scan(
    const float* __restrict__ vecs,
    const unsigned short* __restrict__ c_hi, const unsigned short* __restrict__ c_lo,
    const float* __restrict__ Bn, unsigned int* __restrict__ cand) {
    const int tid = threadIdx.x;
    const int wave = tid >> 6, lane = tid & 63;
    const int col = lane & 15, kg = lane >> 4;
    const int blk = ((blockIdx.x & 7) << 7) | (blockIdx.x >> 3);
    const int t0b = blk * SCAN_TPB;
    const int h = (t0b >> 12) & 7;
    const int t0w = t0b + wave * SCAN_TPW;

    __shared__ short sB[2][2][4096];

    short8 ah[2][4], al[2][4];
#pragma unroll
    for (int mt = 0; mt < 2; ++mt)
#pragma unroll
        for (int ck = 0; ck < 4; ++ck) {
            const float* vp = vecs + (size_t)(t0w + mt * 16 + col) * D_ + ck * 32 + kg * 8;
            float4 q0 = *reinterpret_cast<const float4*>(vp);
            float4 q1 = *reinterpret_cast<const float4*>(vp + 4);
            float f[8] = {q0.x, q0.y, q0.z, q0.w, q1.x, q1.y, q1.z, q1.w};
            short8 h8, l8;
#pragma unroll
            for (int i = 0; i < 8; ++i) {
                unsigned short hu = bf_hi(f[i]);
                unsigned short lu = bf_hi(f[i] - bf_f(hu));
                h8[i] = (short)hu; l8[i] = (short)lu;
            }
            ah[mt][ck] = h8; al[mt][ck] = l8;
        }

    const float* Bnh = Bn + h * S_;
    const float4* ghi = reinterpret_cast<const float4*>(c_hi) + (size_t)h * 16384;
    const float4* glo = reinterpret_cast<const float4*>(c_lo) + (size_t)h * 16384;

    float4 sg0 = ghi[tid], sg1 = ghi[256 + tid], sg2 = glo[tid], sg3 = glo[256 + tid];
    {
        float4* pH = reinterpret_cast<float4*>(&sB[0][0][0]);
        float4* pL = reinterpret_cast<float4*>(&sB[0][1][0]);
        pH[tid] = sg0; pH[256 + tid] = sg1;
        pL[tid] = sg2; pL[256 + tid] = sg3;
    }
    __syncthreads();

    float m1[2][4], m2[2][4];
#pragma unroll
    for (int mt = 0; mt < 2; ++mt)
#pragma unroll
        for (int i = 0; i < 4; ++i) { m1[mt][i] = INFINITY; m2[mt][i] = INFINITY; }

#pragma unroll 1
    for (int c = 0; c < NCHUNK; ++c) {
        const int cur = c & 1, nxt = cur ^ 1;
        if (c + 1 < NCHUNK) {
            const float4* gh = ghi + (size_t)(c + 1) * 512;
            const float4* gl = glo + (size_t)(c + 1) * 512;
            sg0 = gh[tid]; sg1 = gh[256 + tid]; sg2 = gl[tid]; sg3 = gl[256 + tid];
        }
#pragma unroll
        for (int tl = 0; tl < 2; ++tl) {
            const int st = c * 2 + tl;
            short8 bh[4], bl[4];
#pragma unroll
            for (int ck = 0; ck < 4; ++ck) {
                bh[ck] = *reinterpret_cast<const short8*>(&sB[cur][0][tl * 2048 + ck * 512 + lane * 8]);
                bl[ck] = *reinterpret_cast<const short8*>(&sB[cur][1][tl * 2048 + ck * 512 + lane * 8]);
            }
            f32x4 pa0 = {0.f,0.f,0.f,0.f}, pb0 = {0.f,0.f,0.f,0.f}, pc0 = {0.f,0.f,0.f,0.f};
            f32x4 pa1 = {0.f,0.f,0.f,0.f}, pb1 = {0.f,0.f,0.f,0.f}, pc1 = {0.f,0.f,0.f,0.f};
#pragma unroll
            for (int ck = 0; ck < 4; ++ck) {
                pa0 = MFMA(ah[0][ck], bh[ck], pa0);
                pa1 = MFMA(ah[1][ck], bh[ck], pa1);
                pb0 = MFMA(ah[0][ck], bl[ck], pb0);
                pb1 = MFMA(ah[1][ck], bl[ck], pb1);
                pc0 = MFMA(al[0][ck], bh[ck], pc0);
                pc1 = MFMA(al[1][ck], bh[ck], pc1);
            }
            const float bsc = Bnh[st * 16 + col];
#pragma unroll
            for (int i = 0; i < 4; ++i) {
                float d = fmaf(pa0[i] + pb0[i] + pc0[i], -2.f, bsc);
                float pk = __uint_as_float((__float_as_uint(d) & 0xFFFFFFC0u) | (unsigned)st);
                bool cc = pk < m1[0][i];
                m2[0][i] = cc ? m1[0][i] : fminf(pk, m2[0][i]);
                m1[0][i] = cc ? pk : m1[0][i];
                d = fmaf(pa1[i] + pb1[i] + pc1[i], -2.f, bsc);
                pk = __uint_as_float((__float_as_uint(d) & 0xFFFFFFC0u) | (unsigned)st);
                cc = pk < m1[1][i];
                m2[1][i] = cc ? m1[1][i] : fminf(pk, m2[1][i]);
                m1[1][i] = cc ? pk : m1[1][i];
            }
        }
        if (c + 1 < NCHUNK) {
            float4* pH = reinterpret_cast<float4*>(&sB[nxt][0][0]);
            float4* pL = reinterpret_cast<float4*>(&sB[nxt][1][0]);
            pH[tid] = sg0; pH[256 + tid] = sg1;
            pL[tid] = sg2; pL[256 + tid] = sg3;
        }
        __syncthreads();
    }

#pragma unroll
    for (int mt = 0; mt < 2; ++mt)
#pragma unroll
        for (int i = 0; i < 4; ++i) {
            float a1v = m1[mt][i], a2v = m2[mt][i];
            int x1 = (int)((__float_as_uint(a1v) & 63u) << 4) | col;
            int x2 = (int)((__float_as_uint(a2v) & 63u) << 4) | col;
#pragma unroll
            for (int mask = 1; mask < 16; mask <<= 1) {
                float b1 = __shfl_xor(a1v, mask), b2 = __shfl_xor(a2v, mask);
                int y1 = __shfl_xor(x1, mask), y2 = __shfl_xor(x2, mask);
                bool sw = (b1 < a1v) || (b1 == a1v && y1 < x1);
                float w1 = sw ? b1 : a1v; int wi1 = sw ? y1 : x1;
                float r  = sw ? a1v : b1; int ri  = sw ? x1 : y1;
                float w2 = sw ? b2 : a2v; int wi2 = sw ? y2 : x2;
                bool s2 = (r < w2) || (r == w2 && ri < wi2);
                a1v = w1; x1 = wi1;
                a2v = s2 ? r : w2; x2 = s2 ? ri : wi2;
            }
            if (col == 0) {
                int lt = mt * 16 + kg * 4 + i;
                cand[t0w + lt] = (unsigned)x1 | ((unsigned)x2 << 10);
            }
        }
}

// ---------------------------------------------------------------------------
// Rescore: 16-lane cooperative dot per (token,cand) -- coalesced 256B/group
// loads, shfl_xor tree reduce; per-token winner; partials to ws (no atomics).
// ---------------------------------------------------------------------------
__global__ __launch_bounds__(256) void vq_rescore(
    const float* __restrict__ vecs, const float* __restrict__ c_sum,
    const float* __restrict__ c_count, const int* __restrict__ lmask,
    const float* __restrict__ inv_a, const float* __restrict__ Bq,
    const unsigned int* __restrict__ cand,
    double* __restrict__ resC, double* __restrict__ resT,
    long long* __restrict__ resM,
    float* __restrict__ out_hat, float* __restrict__ out_z) {
    const int tid = threadIdx.x;
    const int lane = tid & 63;
    const int g = tid >> 4, j = tid & 15;
    const int blk = ((blockIdx.x & 7) << 7) | (blockIdx.x >> 3);  // XCD swizzle
    const int t0 = blk * RES_TPB;
    const int h = (t0 >> 12) & 7;
    const int b = t0 >> 15;

    __shared__ float sDot[RES_TPB][2];
    __shared__ float sVs[RES_TPB];
    __shared__ int sZ[RES_TPB];
    __shared__ double sC[4], sT[4];
    __shared__ long long sM[4];

    // ---- cooperative dots: 16 rounds x 16 groups ----
#pragma unroll 1
    for (int r = 0; r < 16; ++r) {
        const int p = r * 16 + g;             // pair id 0..255
        const int lt = p >> 1, slot = p & 1;
        const unsigned int cw = cand[t0 + lt];
        const int cidx = slot ? (int)((cw >> 10) & 1023u) : (int)(cw & 1023u);
        const float4* vp = reinterpret_cast<const float4*>(vecs + (size_t)(t0 + lt) * D_);
        const float4* cp = reinterpret_cast<const float4*>(c_sum + ((size_t)h * S_ + cidx) * D_);
        float4 qa = vp[j], qb = vp[16 + j];
        float4 pa = cp[j], pb = cp[16 + j];
        float dot = qa.x * pa.x + qa.y * pa.y + qa.z * pa.z + qa.w * pa.w
                  + qb.x * pb.x + qb.y * pb.y + qb.z * pb.z + qb.w * pb.w;
        float vs = qa.x * qa.x + qa.y * qa.y + qa.z * qa.z + qa.w * qa.w
                 + qb.x * qb.x + qb.y * qb.y + qb.z * qb.z + qb.w * qb.w;
#pragma unroll
        for (int o = 8; o; o >>= 1) { dot += __shfl_xor(dot, o); vs += __shfl_xor(vs, o); }
        if (j == 0) {
            sDot[lt][slot] = dot;
            if (slot == 0) sVs[lt] = vs;
        }
    }
    __syncthreads();

    // ---- per-token decision + loss partials ----
    double commit = 0.0, tokc = 0.0;
    long long mcnt = 0;
    if (tid < RES_TPB) {
        const int lt = tid, tok = t0 + lt;
        const unsigned int cw = cand[tok];
        const int c0 = (int)(cw & 1023u), c1 = (int)((cw >> 10) & 1023u);
        const float dot0 = sDot[lt][0], dot1 = sDot[lt][1], vs = sVs[lt];
        const float dist0 = vs - 2.f * (inv_a[h * S_ + c0] * dot0) + Bq[h * S_ + c0];
        const float dist1 = vs - 2.f * (inv_a[h * S_ + c1] * dot1) + Bq[h * S_ + c1];
        const bool w0 = (dist0 < dist1) || (dist0 == dist1 && c0 < c1);
        const float dwin = w0 ? dist0 : dist1;
        const int zwin = w0 ? c0 : c1;
        const float dotw = w0 ? dot0 : dot1;
        out_z[tok] = (float)zwin;
        sZ[lt] = zwin;
        const int lm = lmask[b * L_ + (tok & (L_ - 1))];
        const float mask = (float)lm;
        commit = (double)(mask * fmaxf(dwin, 0.f));
        tokc = (double)mask * ((double)dotw + (double)c_count[h * S_ + zwin]);
        if (h == 0) mcnt = lm;
    }
#pragma unroll
    for (int o = 32; o; o >>= 1) {
        commit += __shfl_down(commit, o);
        tokc   += __shfl_down(tokc, o);
        mcnt   += __shfl_down(mcnt, o);
    }
    const int w = tid >> 6;
    if (lane == 0) { sC[w] = commit; sT[w] = tokc; sM[w] = mcnt; }
    __syncthreads();
    if (tid == 0) {
        resC[blockIdx.x] = sC[0] + sC[1] + sC[2] + sC[3];
        resT[blockIdx.x] = sT[0] + sT[1] + sT[2] + sT[3];
        resM[blockIdx.x] = sM[0] + sM[1] + sM[2] + sM[3];
    }

    // ---- vecs_hat: 8 half-waves x 16 rounds, float4 per lane ----
    const int hw = tid >> 5, hl = tid & 31;
#pragma unroll
    for (int r0 = 0; r0 < 16; ++r0) {
        int r = r0 * 8 + hw;
        int z = sZ[r];
        float ivz = inv_a[h * S_ + z];
        float4 p = reinterpret_cast<const float4*>(c_sum + ((size_t)h * S_ + z) * D_)[hl];
        float4 o; o.x = p.x * ivz; o.y = p.y * ivz; o.z = p.z * ivz; o.w = p.w * ivz;
        reinterpret_cast<float4*>(out_hat + (size_t)(t0 + r) * D_)[hl] = o;
    }
}

// ---------------------------------------------------------------------------
// Final: deterministic sums of per-block partials -> two scalar outputs.
// ---------------------------------------------------------------------------
__global__ __launch_bounds__(256) void vq_final(
    const double* __restrict__ prepPart, const double* __restrict__ resC,
    const double* __restrict__ resT, const long long* __restrict__ resM,
    float* __restrict__ out_sc) {
    const int tid = threadIdx.x;
    double cs = 0.0, cm = 0.0, tk = 0.0;
    long long mk = 0;
    for (int i = tid; i < PREP_GRID; i += 256) cs += prepPart[i];
    for (int i = tid; i < RES_GRID; i += 256) { cm += resC[i]; tk += resT[i]; mk += resM[i]; }
    __shared__ double aC[4], aM[4], aT[4];
    __shared__ long long aK[4];
#pragma unroll
    for (int o = 32; o; o >>= 1) {
        cs += __shfl_down(cs, o);
        cm += __shfl_down(cm, o);
        tk += __shfl_down(tk, o);
        mk += __shfl_down(mk, o);
    }
    const int w = tid >> 6;
    if ((tid & 63) == 0) { aC[w] = cs; aM[w] = cm; aT[w] = tk; aK[w] = mk; }
    __syncthreads();
    if (tid == 0) {
        double CS = aC[0] + aC[1] + aC[2] + aC[3];
        double CM = aM[0] + aM[1] + aM[2] + aM[3];
        double TK = aT[0] + aT[1] + aT[2] + aT[3];
        double NT = (double)(aK[0] + aK[1] + aK[2] + aK[3]);
        if (NT < 1.0) NT = 1.0;
        out_sc[0] = (float)(CM / ((double)H_ * NT));
        out_sc[1] = (float)(0.01 * (CS - TK));
    }
}

extern "C" void kernel_launch(void* const* d_in, const int* in_sizes, int n_in,
                              void* d_out, int out_size, void* d_ws, size_t ws_size,
                              hipStream_t stream) {
    const float* vecs    = (const float*)d_in[0];
    const float* c_sum   = (const float*)d_in[1];
    const float* c_count = (const float*)d_in[2];
    const int*   lmask   = (const int*)d_in[3];

    char* ws = (char*)d_ws;
    unsigned short* c_hi = (unsigned short*)(ws + WS_CHI);
    unsigned short* c_lo = (unsigned short*)(ws + WS_CLO);
    float* Bn  = (float*)(ws + WS_BN);
    float* inv = (float*)(ws + WS_INV);
    float* Bq  = (float*)(ws + WS_BQ);
    unsigned int* cand = (unsigned int*)(ws + WS_CAND);
    double* prepPart = (double*)(ws + WS_PREPP);
    double* resC = (double*)(ws + WS_RESC);
    double* resT = (double*)(ws + WS_REST);
    long long* resM = (long long*)(ws + WS_RESM);

    float* out = (float*)d_out;
    float* out_sc = out + (size_t)out_size - 2;
    float* out_z  = out_sc - (size_t)NTOK;

    vq_prep<<<PREP_GRID, 256, 0, stream>>>(c_sum, c_count, c_hi, c_lo, Bn, inv, Bq, prepPart);
    vq_scan<<<SCAN_GRID, SCAN_BLK, 0, stream>>>(vecs, c_hi, c_lo, Bn, cand);
    vq_rescore<<<RES_GRID, 256, 0, stream>>>(vecs, c_sum, c_count, lmask, inv, Bq,
                                             cand, resC, resT, resM, out, out_z);
    vq_final<<<1, 256, 0, stream>>>(prepPart, resC, resT, resM, out_sc);
}